// Round 3
// baseline (177.521 us; speedup 1.0000x reference)
//
#include <hip/hip_runtime.h>
#include <hip/hip_bf16.h>

// Problem constants (BertMultiPooler: B=32, S=4096, H=768, K=64)
#define NB 32
#define NS 4096
#define NH 768
#define NK 64
#define NM (NB * NK)         // 2048 output rows
#define ND (2 * NH)          // 1536 GEMM reduction dim
#define KT_TILES (ND / 64)   // 24 GEMM K-tiles of 64
#define POOL_GRID 1024       // persistent pool blocks (12 waves/CU)

typedef short short8 __attribute__((ext_vector_type(8)));
typedef float floatx4 __attribute__((ext_vector_type(4)));

__device__ __forceinline__ unsigned short f2bf(float f) {
    union { float f; unsigned u; } v; v.f = f;
    unsigned r = v.u + 0x7FFFu + ((v.u >> 16) & 1u);   // RNE to bf16
    return (unsigned short)(r >> 16);
}

#define ACC4(s, p) { s.x += p.x; s.y += p.y; s.z += p.z; s.w += p.w; }

// ---------------------------------------------------------------------------
// Kernel 1: build Wc[n][k] (bf16): k<768 -> W_dense[n][k], else W_tab[n][k-768]
// Also initializes the pool ticket counter (block 0, thread 0).
// ---------------------------------------------------------------------------
__global__ __launch_bounds__(256) void wconv_kernel(const float* __restrict__ Wd,
                                                    const float* __restrict__ Wt,
                                                    unsigned short* __restrict__ Wc,
                                                    int* __restrict__ ticket) {
    if (blockIdx.x == 0 && threadIdx.x == 0) *ticket = POOL_GRID;
    int i = blockIdx.x * blockDim.x + threadIdx.x;
    const int total = NH * ND / 4;
    if (i >= total) return;
    int e = i * 4;
    int n = e / ND;
    int k = e % ND;
    float4 v = (k < NH) ? *(const float4*)&Wd[n * NH + k]
                        : *(const float4*)&Wt[n * NH + (k - NH)];
    ushort4 o;
    o.x = f2bf(v.x); o.y = f2bf(v.y); o.z = f2bf(v.z); o.w = f2bf(v.w);
    *(ushort4*)&Wc[e] = o;
}

// ---------------------------------------------------------------------------
// Kernel 2: segment-mean pool + tab gather -> X (bf16, 2048 x 1536)
// Persistent blocks with dynamic ticket assignment (fixes static-residency
// makespan imbalance of Exp-distributed segment lengths). No data atomics.
// 192 threads; thread t owns columns 4t..4t+3; register ping-pong for ~8
// loads in flight per wave.
// ---------------------------------------------------------------------------
__global__ __launch_bounds__(192) void pool_kernel(const float* __restrict__ hs,
                                                   const int* __restrict__ cls,
                                                   const int* __restrict__ tlen,
                                                   unsigned short* __restrict__ X,
                                                   int* __restrict__ ticket) {
    __shared__ int sseg;
    const int t = threadIdx.x;
    int seg = blockIdx.x;

    for (;;) {
        if (seg >= NM) return;

        const int b = seg >> 6, k = seg & 63;
        const int start = cls[seg * 2 + 1];
        int end = (k == NK - 1) ? NS : cls[seg * 2 + 3];
        const int tl = tlen[b];
        if (end > tl) end = tl;
        const int cnt = end - start;

        const float4* base = (const float4*)(hs + ((size_t)b * NS + (size_t)start) * NH) + t;

        float4 s0 = {0,0,0,0}, s1 = {0,0,0,0}, s2 = {0,0,0,0}, s3 = {0,0,0,0};
        int r = 0;
        if (cnt >= 4) {
            float4 p0 = base[0 * (NH/4)], p1 = base[1 * (NH/4)],
                   p2 = base[2 * (NH/4)], p3 = base[3 * (NH/4)];
            for (r = 4; r + 4 <= cnt; r += 4) {
                float4 q0 = base[(size_t)(r+0) * (NH/4)];
                float4 q1 = base[(size_t)(r+1) * (NH/4)];
                float4 q2 = base[(size_t)(r+2) * (NH/4)];
                float4 q3 = base[(size_t)(r+3) * (NH/4)];
                ACC4(s0, p0) ACC4(s1, p1) ACC4(s2, p2) ACC4(s3, p3)
                p0 = q0; p1 = q1; p2 = q2; p3 = q3;
            }
            ACC4(s0, p0) ACC4(s1, p1) ACC4(s2, p2) ACC4(s3, p3)
        }
        for (; r < cnt; ++r) {
            float4 v = base[(size_t)r * (NH/4)];
            ACC4(s0, v)
        }
        ACC4(s0, s1) ACC4(s2, s3) ACC4(s0, s2)

        const float inv = 1.0f / (float)cnt;

        // tab gather: row `start` of batch cls[seg*2]
        const int tb = cls[seg * 2];
        float4 tv = *((const float4*)(hs + ((size_t)tb * NS + (size_t)start) * NH) + t);

        ushort4 po, ta;
        po.x = f2bf(s0.x * inv); po.y = f2bf(s0.y * inv);
        po.z = f2bf(s0.z * inv); po.w = f2bf(s0.w * inv);
        ta.x = f2bf(tv.x); ta.y = f2bf(tv.y); ta.z = f2bf(tv.z); ta.w = f2bf(tv.w);

        unsigned short* xr = X + (size_t)seg * ND;
        *(ushort4*)&xr[t * 4]      = po;   // pooled half  [0,768)
        *(ushort4*)&xr[NH + t * 4] = ta;   // tab half     [768,1536)

        __syncthreads();                    // all lanes done with current sseg
        if (t == 0) sseg = atomicAdd(ticket, 1);
        __syncthreads();
        seg = sseg;
    }
}

// ---------------------------------------------------------------------------
// Kernel 3: out = tanh(X @ Wc^T + b_dense + b_tab)
// M=2048, N=768, K=1536. 64x64 block tile, 4 waves (2x2), BK=64,
// LDS double-buffer, ONE barrier/iter, prefetch distance 2 (named reg sets).
// Rows padded to 72 shorts (144B) -> 2-way max bank aliasing on ds_read_b128.
// ---------------------------------------------------------------------------
__global__ __launch_bounds__(256) void gemm_kernel(const unsigned short* __restrict__ X,
                                                   const unsigned short* __restrict__ Wc,
                                                   const float* __restrict__ bd,
                                                   const float* __restrict__ bt,
                                                   float* __restrict__ out) {
    __shared__ unsigned short Al[2][64 * 72];
    __shared__ unsigned short Bl[2][64 * 72];

    const int m0 = blockIdx.x * 64;
    const int n0 = blockIdx.y * 64;
    const int tid  = threadIdx.x;
    const int lane = tid & 63;
    const int wv   = tid >> 6;
    const int wr   = wv >> 1;          // wave row (0..1)
    const int wc   = wv & 1;           // wave col (0..1)
    const int lrow = lane & 15;
    const int hi   = lane >> 4;        // 0..3
    const int srow = tid >> 2;         // staging row 0..63
    const int sc   = tid & 3;          // staging chunk base (writes sc, sc+4)

    floatx4 acc[2][2] = {};

    const uint4* gA = (const uint4*)(X  + (size_t)(m0 + srow) * ND);
    const uint4* gB = (const uint4*)(Wc + (size_t)(n0 + srow) * ND);

    uint4 vA0[2], vA1[2], vB0[2], vB1[2];   // two named prefetch sets (rule #20)

    // prologue: tile0 -> set0 -> LDS buf0 ; tile1 -> set1 (held in regs)
    vA0[0] = gA[sc];     vA0[1] = gA[sc + 4];
    vB0[0] = gB[sc];     vB0[1] = gB[sc + 4];
    *(uint4*)&Al[0][srow * 72 + sc * 8]       = vA0[0];
    *(uint4*)&Al[0][srow * 72 + (sc + 4) * 8] = vA0[1];
    *(uint4*)&Bl[0][srow * 72 + sc * 8]       = vB0[0];
    *(uint4*)&Bl[0][srow * 72 + (sc + 4) * 8] = vB0[1];
    vA1[0] = gA[8 + sc]; vA1[1] = gA[8 + sc + 4];
    vB1[0] = gB[8 + sc]; vB1[1] = gB[8 + sc + 4];

#define GEMM_COMPUTE(RB)                                                             \
    _Pragma("unroll")                                                                \
    for (int ks = 0; ks < 2; ++ks) {                                                 \
        short8 a0 = *(const short8*)&Al[RB][(wr * 32 +      lrow) * 72 + ks * 32 + hi * 8]; \
        short8 a1 = *(const short8*)&Al[RB][(wr * 32 + 16 + lrow) * 72 + ks * 32 + hi * 8]; \
        short8 b0 = *(const short8*)&Bl[RB][(wc * 32 +      lrow) * 72 + ks * 32 + hi * 8]; \
        short8 b1 = *(const short8*)&Bl[RB][(wc * 32 + 16 + lrow) * 72 + ks * 32 + hi * 8]; \
        acc[0][0] = __builtin_amdgcn_mfma_f32_16x16x32_bf16(a0, b0, acc[0][0], 0, 0, 0);    \
        acc[0][1] = __builtin_amdgcn_mfma_f32_16x16x32_bf16(a0, b1, acc[0][1], 0, 0, 0);    \
        acc[1][0] = __builtin_amdgcn_mfma_f32_16x16x32_bf16(a1, b0, acc[1][0], 0, 0, 0);    \
        acc[1][1] = __builtin_amdgcn_mfma_f32_16x16x32_bf16(a1, b1, acc[1][1], 0, 0, 0);    \
    }

// iter kt (parity P): sync; prefetch tile kt+2 -> set P; compute buf P;
// store set (P^1), which holds tile kt+1, -> buf (P^1)
#define GEMM_ITER(kt, VA_L, VB_L, VA_S, VB_S, P)                                     \
    {                                                                                \
        __syncthreads();                                                             \
        if ((kt) + 2 < KT_TILES) {                                                   \
            VA_L[0] = gA[((kt) + 2) * 8 + sc]; VA_L[1] = gA[((kt) + 2) * 8 + sc + 4];\
            VB_L[0] = gB[((kt) + 2) * 8 + sc]; VB_L[1] = gB[((kt) + 2) * 8 + sc + 4];\
        }                                                                            \
        GEMM_COMPUTE(P)                                                              \
        if ((kt) + 1 < KT_TILES) {                                                   \
            *(uint4*)&Al[P ^ 1][srow * 72 + sc * 8]       = VA_S[0];                 \
            *(uint4*)&Al[P ^ 1][srow * 72 + (sc + 4) * 8] = VA_S[1];                 \
            *(uint4*)&Bl[P ^ 1][srow * 72 + sc * 8]       = VB_S[0];                 \
            *(uint4*)&Bl[P ^ 1][srow * 72 + (sc + 4) * 8] = VB_S[1];                 \
        }                                                                            \
    }

    for (int kt = 0; kt < KT_TILES; kt += 2) {
        GEMM_ITER(kt,     vA0, vB0, vA1, vB1, 0)
        GEMM_ITER(kt + 1, vA1, vB1, vA0, vB0, 1)
    }
#undef GEMM_ITER
#undef GEMM_COMPUTE

    // Epilogue: C/D layout col = lane&15, row = (lane>>4)*4 + reg  [HW-verified]
    for (int mi = 0; mi < 2; ++mi) {
        for (int ni = 0; ni < 2; ++ni) {
            int col  = n0 + wc * 32 + ni * 16 + lrow;
            float bias = bd[col] + bt[col];
            int rowb = m0 + wr * 32 + mi * 16 + hi * 4;
            #pragma unroll
            for (int j = 0; j < 4; ++j) {
                out[(size_t)(rowb + j) * NH + col] = tanhf(acc[mi][ni][j] + bias);
            }
        }
    }
}

// ---------------------------------------------------------------------------
extern "C" void kernel_launch(void* const* d_in, const int* in_sizes, int n_in,
                              void* d_out, int out_size, void* d_ws, size_t ws_size,
                              hipStream_t stream) {
    const float* hs  = (const float*)d_in[0];   // hidden_states (B,S,H) f32
    const float* Wd  = (const float*)d_in[1];   // W_dense (H,H)
    const float* bd  = (const float*)d_in[2];   // b_dense (H,)
    const float* Wt  = (const float*)d_in[3];   // W_tab (H,H)
    const float* bt  = (const float*)d_in[4];   // b_tab (H,)
    const int*   cls = (const int*)d_in[5];     // cls_indexes (B*K, 2) as int32
    const int*   tl  = (const int*)d_in[6];     // table_length (B,) as int32
    float* out = (float*)d_out;

    // ws layout: [ticket (256B pad)] [Wc bf16 768x1536] [X bf16 2048x1536]
    int*            ticket = (int*)d_ws;
    unsigned short* Wc     = (unsigned short*)((char*)d_ws + 256);
    unsigned short* X      = Wc + (size_t)NH * ND;

    // weights convert + ticket init
    wconv_kernel<<<dim3((NH * ND / 4 + 255) / 256), 256, 0, stream>>>(Wd, Wt, Wc, ticket);
    // segment-mean pooling + tab gather (dynamic ticket balancing)
    pool_kernel<<<dim3(POOL_GRID), 192, 0, stream>>>(hs, cls, tl, X, ticket);
    // fused GEMM + bias + tanh
    gemm_kernel<<<dim3(NM / 64, NH / 64), 256, 0, stream>>>(X, Wc, bd, bt, out);
}

// Round 4
// 159.659 us; speedup vs baseline: 1.1119x; 1.1119x over previous
//
#include <hip/hip_runtime.h>
#include <hip/hip_bf16.h>

// Problem constants (BertMultiPooler: B=32, S=4096, H=768, K=64)
#define NB 32
#define NS 4096
#define NH 768
#define NK 64
#define NM (NB * NK)         // 2048 output rows
#define ND (2 * NH)          // 1536 GEMM reduction dim
#define KT_TILES (ND / 64)   // 24 GEMM K-tiles of 64

typedef short short8 __attribute__((ext_vector_type(8)));
typedef float floatx4 __attribute__((ext_vector_type(4)));

__device__ __forceinline__ unsigned short f2bf(float f) {
    union { float f; unsigned u; } v; v.f = f;
    unsigned r = v.u + 0x7FFFu + ((v.u >> 16) & 1u);   // RNE to bf16
    return (unsigned short)(r >> 16);
}

#define ACC4(s, p) { s.x += p.x; s.y += p.y; s.z += p.z; s.w += p.w; }

// ---------------------------------------------------------------------------
// Kernel 1: build Wc[n][k] (bf16): k<768 -> W_dense[n][k], else W_tab[n][k-768]
// ---------------------------------------------------------------------------
__global__ __launch_bounds__(256) void wconv_kernel(const float* __restrict__ Wd,
                                                    const float* __restrict__ Wt,
                                                    unsigned short* __restrict__ Wc) {
    int i = blockIdx.x * blockDim.x + threadIdx.x;
    const int total = NH * ND / 4;
    if (i >= total) return;
    int e = i * 4;
    int n = e / ND;
    int k = e % ND;
    float4 v = (k < NH) ? *(const float4*)&Wd[n * NH + k]
                        : *(const float4*)&Wt[n * NH + (k - NH)];
    ushort4 o;
    o.x = f2bf(v.x); o.y = f2bf(v.y); o.z = f2bf(v.z); o.w = f2bf(v.w);
    *(ushort4*)&Wc[e] = o;
}

// ---------------------------------------------------------------------------
// Kernel 2: segment-mean pool + tab gather -> X (bf16, 2048 x 1536)
// One block per segment (HW dispatcher refills -> natural load balance).
// 768 threads = 4 row-groups x 192 column-threads; row-group rg sums rows
// start+rg, start+rg+4, ... with an 8-deep unroll (8 loads in flight/lane);
// LDS reduce combines the 4 partials. 4x parallelism on straggler segments.
// ---------------------------------------------------------------------------
__global__ __launch_bounds__(768) void pool_kernel(const float* __restrict__ hs,
                                                   const int* __restrict__ cls,
                                                   const int* __restrict__ tlen,
                                                   unsigned short* __restrict__ X) {
    __shared__ float4 red[3][192];

    const int seg = blockIdx.x;          // 0..2047
    const int b = seg >> 6, k = seg & 63;
    const int start = cls[seg * 2 + 1];
    int end = (k == NK - 1) ? NS : cls[seg * 2 + 3];
    const int tl = tlen[b];
    if (end > tl) end = tl;
    const int cnt = end - start;

    const int t  = threadIdx.x;
    const int rg = t / 192;              // row-group 0..3
    const int c  = t % 192;              // owns columns 4c..4c+3

    // rows of this group: start+rg + 4*i, i in [0, n)
    const int n = (cnt - rg + 3) >> 2;   // may be <=0 -> loops skipped

    const float4* base = (const float4*)(hs + ((size_t)b * NS + start + rg) * NH) + c;
    // stride between this group's consecutive rows = 4 rows = NH float4s

    float4 s0 = {0,0,0,0}, s1 = {0,0,0,0}, s2 = {0,0,0,0}, s3 = {0,0,0,0};
    int i = 0;
    for (; i + 8 <= n; i += 8) {
        float4 v0 = base[(size_t)(i + 0) * NH];
        float4 v1 = base[(size_t)(i + 1) * NH];
        float4 v2 = base[(size_t)(i + 2) * NH];
        float4 v3 = base[(size_t)(i + 3) * NH];
        float4 v4 = base[(size_t)(i + 4) * NH];
        float4 v5 = base[(size_t)(i + 5) * NH];
        float4 v6 = base[(size_t)(i + 6) * NH];
        float4 v7 = base[(size_t)(i + 7) * NH];
        ACC4(s0, v0) ACC4(s1, v1) ACC4(s2, v2) ACC4(s3, v3)
        ACC4(s0, v4) ACC4(s1, v5) ACC4(s2, v6) ACC4(s3, v7)
    }
    for (; i < n; ++i) {
        float4 v = base[(size_t)i * NH];
        ACC4(s0, v)
    }
    ACC4(s0, s1) ACC4(s2, s3) ACC4(s0, s2)

    if (rg > 0) red[rg - 1][c] = s0;
    __syncthreads();
    if (rg == 0) {
        float4 r0 = red[0][c], r1 = red[1][c], r2 = red[2][c];
        ACC4(s0, r0) ACC4(s0, r1) ACC4(s0, r2)

        const float inv = 1.0f / (float)cnt;

        const int tb = cls[seg * 2];
        float4 tv = *((const float4*)(hs + ((size_t)tb * NS + start) * NH) + c);

        ushort4 po, ta;
        po.x = f2bf(s0.x * inv); po.y = f2bf(s0.y * inv);
        po.z = f2bf(s0.z * inv); po.w = f2bf(s0.w * inv);
        ta.x = f2bf(tv.x); ta.y = f2bf(tv.y); ta.z = f2bf(tv.z); ta.w = f2bf(tv.w);

        unsigned short* xr = X + (size_t)seg * ND;
        *(ushort4*)&xr[c * 4]      = po;   // pooled half  [0,768)
        *(ushort4*)&xr[NH + c * 4] = ta;   // tab half     [768,1536)
    }
}

// ---------------------------------------------------------------------------
// Kernel 3: out = tanh(X @ Wc^T + b_dense + b_tab)
// M=2048, N=768, K=1536. 64x64 block tile, 4 waves (2x2), BK=64,
// LDS double-buffer, ONE barrier/iter, prefetch distance 2 (named reg sets).
// Rows padded to 72 shorts (144B) -> 2-way max bank aliasing on ds_read_b128.
// ---------------------------------------------------------------------------
__global__ __launch_bounds__(256) void gemm_kernel(const unsigned short* __restrict__ X,
                                                   const unsigned short* __restrict__ Wc,
                                                   const float* __restrict__ bd,
                                                   const float* __restrict__ bt,
                                                   float* __restrict__ out) {
    __shared__ unsigned short Al[2][64 * 72];
    __shared__ unsigned short Bl[2][64 * 72];

    const int m0 = blockIdx.x * 64;
    const int n0 = blockIdx.y * 64;
    const int tid  = threadIdx.x;
    const int lane = tid & 63;
    const int wv   = tid >> 6;
    const int wr   = wv >> 1;          // wave row (0..1)
    const int wc   = wv & 1;           // wave col (0..1)
    const int lrow = lane & 15;
    const int hi   = lane >> 4;        // 0..3
    const int srow = tid >> 2;         // staging row 0..63
    const int sc   = tid & 3;          // staging chunk base (writes sc, sc+4)

    floatx4 acc[2][2] = {};

    const uint4* gA = (const uint4*)(X  + (size_t)(m0 + srow) * ND);
    const uint4* gB = (const uint4*)(Wc + (size_t)(n0 + srow) * ND);

    uint4 vA0[2], vA1[2], vB0[2], vB1[2];   // two named prefetch sets (rule #20)

    // prologue: tile0 -> set0 -> LDS buf0 ; tile1 -> set1 (held in regs)
    vA0[0] = gA[sc];     vA0[1] = gA[sc + 4];
    vB0[0] = gB[sc];     vB0[1] = gB[sc + 4];
    *(uint4*)&Al[0][srow * 72 + sc * 8]       = vA0[0];
    *(uint4*)&Al[0][srow * 72 + (sc + 4) * 8] = vA0[1];
    *(uint4*)&Bl[0][srow * 72 + sc * 8]       = vB0[0];
    *(uint4*)&Bl[0][srow * 72 + (sc + 4) * 8] = vB0[1];
    vA1[0] = gA[8 + sc]; vA1[1] = gA[8 + sc + 4];
    vB1[0] = gB[8 + sc]; vB1[1] = gB[8 + sc + 4];

#define GEMM_COMPUTE(RB)                                                             \
    _Pragma("unroll")                                                                \
    for (int ks = 0; ks < 2; ++ks) {                                                 \
        short8 a0 = *(const short8*)&Al[RB][(wr * 32 +      lrow) * 72 + ks * 32 + hi * 8]; \
        short8 a1 = *(const short8*)&Al[RB][(wr * 32 + 16 + lrow) * 72 + ks * 32 + hi * 8]; \
        short8 b0 = *(const short8*)&Bl[RB][(wc * 32 +      lrow) * 72 + ks * 32 + hi * 8]; \
        short8 b1 = *(const short8*)&Bl[RB][(wc * 32 + 16 + lrow) * 72 + ks * 32 + hi * 8]; \
        acc[0][0] = __builtin_amdgcn_mfma_f32_16x16x32_bf16(a0, b0, acc[0][0], 0, 0, 0);    \
        acc[0][1] = __builtin_amdgcn_mfma_f32_16x16x32_bf16(a0, b1, acc[0][1], 0, 0, 0);    \
        acc[1][0] = __builtin_amdgcn_mfma_f32_16x16x32_bf16(a1, b0, acc[1][0], 0, 0, 0);    \
        acc[1][1] = __builtin_amdgcn_mfma_f32_16x16x32_bf16(a1, b1, acc[1][1], 0, 0, 0);    \
    }

// iter kt (parity P): sync; prefetch tile kt+2 -> set P; compute buf P;
// store set (P^1), which holds tile kt+1, -> buf (P^1)
#define GEMM_ITER(kt, VA_L, VB_L, VA_S, VB_S, P)                                     \
    {                                                                                \
        __syncthreads();                                                             \
        if ((kt) + 2 < KT_TILES) {                                                   \
            VA_L[0] = gA[((kt) + 2) * 8 + sc]; VA_L[1] = gA[((kt) + 2) * 8 + sc + 4];\
            VB_L[0] = gB[((kt) + 2) * 8 + sc]; VB_L[1] = gB[((kt) + 2) * 8 + sc + 4];\
        }                                                                            \
        GEMM_COMPUTE(P)                                                              \
        if ((kt) + 1 < KT_TILES) {                                                   \
            *(uint4*)&Al[P ^ 1][srow * 72 + sc * 8]       = VA_S[0];                 \
            *(uint4*)&Al[P ^ 1][srow * 72 + (sc + 4) * 8] = VA_S[1];                 \
            *(uint4*)&Bl[P ^ 1][srow * 72 + sc * 8]       = VB_S[0];                 \
            *(uint4*)&Bl[P ^ 1][srow * 72 + (sc + 4) * 8] = VB_S[1];                 \
        }                                                                            \
    }

    for (int kt = 0; kt < KT_TILES; kt += 2) {
        GEMM_ITER(kt,     vA0, vB0, vA1, vB1, 0)
        GEMM_ITER(kt + 1, vA1, vB1, vA0, vB0, 1)
    }
#undef GEMM_ITER
#undef GEMM_COMPUTE

    // Epilogue: C/D layout col = lane&15, row = (lane>>4)*4 + reg  [HW-verified]
    for (int mi = 0; mi < 2; ++mi) {
        for (int ni = 0; ni < 2; ++ni) {
            int col  = n0 + wc * 32 + ni * 16 + lrow;
            float bias = bd[col] + bt[col];
            int rowb = m0 + wr * 32 + mi * 16 + hi * 4;
            #pragma unroll
            for (int j = 0; j < 4; ++j) {
                out[(size_t)(rowb + j) * NH + col] = tanhf(acc[mi][ni][j] + bias);
            }
        }
    }
}

// ---------------------------------------------------------------------------
extern "C" void kernel_launch(void* const* d_in, const int* in_sizes, int n_in,
                              void* d_out, int out_size, void* d_ws, size_t ws_size,
                              hipStream_t stream) {
    const float* hs  = (const float*)d_in[0];   // hidden_states (B,S,H) f32
    const float* Wd  = (const float*)d_in[1];   // W_dense (H,H)
    const float* bd  = (const float*)d_in[2];   // b_dense (H,)
    const float* Wt  = (const float*)d_in[3];   // W_tab (H,H)
    const float* bt  = (const float*)d_in[4];   // b_tab (H,)
    const int*   cls = (const int*)d_in[5];     // cls_indexes (B*K, 2) as int32
    const int*   tl  = (const int*)d_in[6];     // table_length (B,) as int32
    float* out = (float*)d_out;

    // ws layout: [Wc bf16 768x1536] [X bf16 2048x1536]
    unsigned short* Wc = (unsigned short*)d_ws;
    unsigned short* X  = Wc + (size_t)NH * ND;

    // weights convert
    wconv_kernel<<<dim3((NH * ND / 4 + 255) / 256), 256, 0, stream>>>(Wd, Wt, Wc);
    // segment-mean pooling + tab gather (one block/segment, 4-way row-parallel)
    pool_kernel<<<dim3(NM), 768, 0, stream>>>(hs, cls, tl, X);
    // fused GEMM + bias + tanh
    gemm_kernel<<<dim3(NM / 64, NH / 64), 256, 0, stream>>>(X, Wc, bd, bt, out);
}